// Round 7
// baseline (283.933 us; speedup 1.0000x reference)
//
#include <hip/hip_runtime.h>
#include <math.h>

#define N_NODES 100000
#define N_EDGES 1600000
#define HIDDEN 128

// ---- binning geometry ------------------------------------------------------
#define NBINS      256
#define BIN_NODES  391        // 256*391 = 100096 >= 100000
#define BIN_CAP    16384      // records/bin: mean 12512, sigma ~112
#define A_THREADS  1024
#define A_EPT      2          // edges per thread (int2-vectorized)
#define A_EPB      (A_THREADS * A_EPT)                    // 2048 edges/block
#define A_BLOCKS   ((N_EDGES + A_EPB - 1) / A_EPB)        // 782
#define B_THREADS  1024

// Record layout: [26:17]=own-local node (9b), [16:0]=other node id (17b).
// Sign trick: both endpoints' contributions are normalize(pos[other]-pos[own]),
// so no side/sign bit is needed and phase B never touches eidx.

// Native 4-wide float vector — required for __builtin_nontemporal_store.
typedef float vfloat4 __attribute__((ext_vector_type(4)));

// ---------------------------------------------------------------------------
// Kernel A0: zero the 256 bin cursors.
// ---------------------------------------------------------------------------
__global__ void zero_cursors_kernel(unsigned* __restrict__ cur) {
    cur[threadIdx.x] = 0u;
}

// ---------------------------------------------------------------------------
// Kernel A: bin edges. Each edge emits a record into bin(row) and bin(col).
// Per-block LDS counts -> one global cursor atomicAdd per (block,bin).
// ---------------------------------------------------------------------------
__global__ __launch_bounds__(A_THREADS) void bin_edges_kernel(
    const int* __restrict__ eidx,
    unsigned* __restrict__ cursors,
    unsigned* __restrict__ region)
{
    __shared__ unsigned cnt[NBINS];
    __shared__ unsigned base[NBINS];
    if (threadIdx.x < NBINS) cnt[threadIdx.x] = 0u;
    __syncthreads();

    const int e0 = blockIdx.x * A_EPB + threadIdx.x * 2;
    const bool valid = (e0 < N_EDGES);   // N_EDGES even -> e0+1 also valid

    unsigned r[A_EPT], c[A_EPT], br[A_EPT], bc[A_EPT], orow[A_EPT], ocol[A_EPT];

    if (valid) {
        int2 rr = *reinterpret_cast<const int2*>(eidx + e0);
        int2 cc = *reinterpret_cast<const int2*>(eidx + N_EDGES + e0);
        r[0] = (unsigned)rr.x; r[1] = (unsigned)rr.y;
        c[0] = (unsigned)cc.x; c[1] = (unsigned)cc.y;
        #pragma unroll
        for (int k = 0; k < A_EPT; ++k) {
            br[k] = r[k] / BIN_NODES;
            bc[k] = c[k] / BIN_NODES;
            orow[k] = atomicAdd(&cnt[br[k]], 1u);
            ocol[k] = atomicAdd(&cnt[bc[k]], 1u);
        }
    }
    __syncthreads();

    if (threadIdx.x < NBINS)
        base[threadIdx.x] = atomicAdd(&cursors[threadIdx.x], cnt[threadIdx.x]);
    __syncthreads();

    if (valid) {
        #pragma unroll
        for (int k = 0; k < A_EPT; ++k) {
            region[br[k] * BIN_CAP + base[br[k]] + orow[k]] =
                ((r[k] - br[k] * BIN_NODES) << 17) | c[k];
            region[bc[k] * BIN_CAP + base[bc[k]] + ocol[k]] =
                ((c[k] - bc[k] * BIN_NODES) << 17) | r[k];
        }
    }
}

// ---------------------------------------------------------------------------
// Kernel B: one block per bin. Coalesced uint4 record loads; own-pos from an
// LDS stage, other-pos from L2-resident pos; accumulate du in LDS; write du
// slice + fused angular rows. (Unchanged from R6.)
// ---------------------------------------------------------------------------
__device__ __forceinline__ void proc_rec(unsigned rec,
                                         const float* __restrict__ posLDS,
                                         const float* __restrict__ pos,
                                         float* __restrict__ acc) {
    unsigned other = rec & 0x1FFFFu;
    unsigned local = rec >> 17;
    float sx = posLDS[local * 3 + 0];
    float sy = posLDS[local * 3 + 1];
    float sz = posLDS[local * 3 + 2];
    float dx = pos[other * 3 + 0] - sx;
    float dy = pos[other * 3 + 1] - sy;
    float dz = pos[other * 3 + 2] - sz;
    float inv = 1.0f / (sqrtf(dx * dx + dy * dy + dz * dz) + 1e-8f);
    atomicAdd(&acc[local * 3 + 0], dx * inv);
    atomicAdd(&acc[local * 3 + 1], dy * inv);
    atomicAdd(&acc[local * 3 + 2], dz * inv);
}

__global__ __launch_bounds__(B_THREADS) void accumulate_kernel(
    const float* __restrict__ pos,
    const unsigned* __restrict__ cursors,
    const unsigned* __restrict__ region,
    float* __restrict__ du,
    float* __restrict__ ang)
{
    __shared__ float acc[BIN_NODES * 3];     // 4692 B
    __shared__ float posLDS[BIN_NODES * 3];  // 4692 B
    const unsigned b = blockIdx.x;
    const unsigned nodebase = b * BIN_NODES;
    const unsigned nloc = min((unsigned)BIN_NODES,
                              (unsigned)(N_NODES - nodebase));

    for (int i = threadIdx.x; i < BIN_NODES * 3; i += B_THREADS) acc[i] = 0.0f;
    for (unsigned i = threadIdx.x; i < nloc * 3; i += B_THREADS)
        posLDS[i] = pos[(size_t)nodebase * 3 + i];
    __syncthreads();

    const unsigned n = cursors[b];
    const unsigned* __restrict__ reg = region + (size_t)b * BIN_CAP;
    const unsigned n4 = n & ~3u;

    for (unsigned i = threadIdx.x * 4; i < n4; i += B_THREADS * 4) {
        uint4 rc = *reinterpret_cast<const uint4*>(reg + i);
        proc_rec(rc.x, posLDS, pos, acc);
        proc_rec(rc.y, posLDS, pos, acc);
        proc_rec(rc.z, posLDS, pos, acc);
        proc_rec(rc.w, posLDS, pos, acc);
    }
    for (unsigned i = n4 + threadIdx.x; i < n; i += B_THREADS)
        proc_rec(reg[i], posLDS, pos, acc);
    __syncthreads();

    for (unsigned i = threadIdx.x; i < nloc * 3; i += B_THREADS)
        du[(size_t)nodebase * 3 + i] = acc[i];

    for (unsigned j = threadIdx.x; j < nloc * 32; j += B_THREADS) {
        unsigned node = j >> 5, c4 = j & 31;
        float x = acc[node * 3 + 0];
        float y = acc[node * 3 + 1];
        float z = acc[node * 3 + 2];
        float a = x * x + y * y + z * z;
        vfloat4 v4 = {a, a, a, a};
        __builtin_nontemporal_store(v4,
            reinterpret_cast<vfloat4*>(ang + (size_t)(nodebase + node) * HIDDEN) + c4);
    }
}

// ---------------------------------------------------------------------------
// Kernel C1: per-edge dihedral scalar only. Full-chip gather kernel; no
// broadcast stores, so gather latency is hidden by massive TLP.
// ---------------------------------------------------------------------------
__global__ __launch_bounds__(256) void dihedral_scalar_kernel(
    const float* __restrict__ pos,
    const int* __restrict__ eidx,
    const float* __restrict__ du,
    float* __restrict__ dvals)
{
    const int e = blockIdx.x * 256 + threadIdx.x;

    int r = eidx[e];
    int c = eidx[N_EDGES + e];

    float dx = pos[c * 3 + 0] - pos[r * 3 + 0];
    float dy = pos[c * 3 + 1] - pos[r * 3 + 1];
    float dz = pos[c * 3 + 2] - pos[r * 3 + 2];
    float dist = sqrtf(dx * dx + dy * dy + dz * dz) + 1e-8f;
    float inv = 1.0f / dist;
    float ux = dx * inv, uy = dy * inv, uz = dz * inv;

    float vix = du[r * 3 + 0], viy = du[r * 3 + 1], viz = du[r * 3 + 2];
    float vjx = du[c * 3 + 0], vjy = du[c * 3 + 1], vjz = du[c * 3 + 2];

    float dvi = vix * ux + viy * uy + viz * uz;
    float dvj = -(vjx * ux + vjy * uy + vjz * uz);

    float wix = vix - dvi * ux;
    float wiy = viy - dvi * uy;
    float wiz = viz - dvi * uz;
    float wjx = vjx + dvj * ux;
    float wjy = vjy + dvj * uy;
    float wjz = vjz + dvj * uz;

    dvals[e] = wix * wjx + wiy * wjy + wiz * wjz;
}

// ---------------------------------------------------------------------------
// Kernel C2: pure broadcast fill — coalesced dvals read -> LDS -> float4 NT
// stores. Structurally identical to the harness fill kernel (~6.7 TB/s).
// ---------------------------------------------------------------------------
__global__ __launch_bounds__(256) void dihedral_fill_kernel(
    const float* __restrict__ dvals,
    float* __restrict__ dih)
{
    __shared__ float vals[256];
    const int e0 = blockIdx.x * 256;
    vals[threadIdx.x] = dvals[e0 + threadIdx.x];
    __syncthreads();

    vfloat4* out = reinterpret_cast<vfloat4*>(dih + (size_t)e0 * HIDDEN);
    #pragma unroll
    for (int it = 0; it < 32; ++it) {
        int i = it * 256 + threadIdx.x;   // 0 .. 8191
        float v = vals[i >> 5];
        vfloat4 v4 = {v, v, v, v};
        __builtin_nontemporal_store(v4, out + i);
    }
}

// ---------------------------------------------------------------------------
// Fallback path (ws too small): R3-style direct global-atomic scatter with
// the original fused dihedral kernel.
// ---------------------------------------------------------------------------
__global__ void zero_du_kernel(float* __restrict__ du, int n) {
    int i = blockIdx.x * blockDim.x + threadIdx.x;
    if (i < n) du[i] = 0.0f;
}

__global__ void edge_scatter_kernel(const float* __restrict__ pos,
                                    const int* __restrict__ eidx,
                                    float* __restrict__ du) {
    int e = blockIdx.x * blockDim.x + threadIdx.x;
    if (e >= N_EDGES) return;
    int r = eidx[e];
    int c = eidx[N_EDGES + e];
    float dx = pos[c * 3 + 0] - pos[r * 3 + 0];
    float dy = pos[c * 3 + 1] - pos[r * 3 + 1];
    float dz = pos[c * 3 + 2] - pos[r * 3 + 2];
    float inv = 1.0f / (sqrtf(dx * dx + dy * dy + dz * dz) + 1e-8f);
    float ux = dx * inv, uy = dy * inv, uz = dz * inv;
    atomicAdd(&du[r * 3 + 0],  ux);
    atomicAdd(&du[r * 3 + 1],  uy);
    atomicAdd(&du[r * 3 + 2],  uz);
    atomicAdd(&du[c * 3 + 0], -ux);
    atomicAdd(&du[c * 3 + 1], -uy);
    atomicAdd(&du[c * 3 + 2], -uz);
}

__global__ void angular_kernel(const float* __restrict__ du,
                               float* __restrict__ ang) {
    int gid = blockIdx.x * blockDim.x + threadIdx.x;
    int node = gid >> 5;
    int c4   = gid & 31;
    float x = du[node * 3 + 0];
    float y = du[node * 3 + 1];
    float z = du[node * 3 + 2];
    float a = x * x + y * y + z * z;
    vfloat4 v4 = {a, a, a, a};
    __builtin_nontemporal_store(v4,
        reinterpret_cast<vfloat4*>(ang + (size_t)node * HIDDEN) + c4);
}

__global__ void dihedral_fused_kernel(const float* __restrict__ pos,
                                      const int* __restrict__ eidx,
                                      const float* __restrict__ du,
                                      float* __restrict__ dih) {
    __shared__ float vals[256];
    const int e0 = blockIdx.x * 256;
    const int e  = e0 + threadIdx.x;
    {
        int r = eidx[e];
        int c = eidx[N_EDGES + e];
        float dx = pos[c * 3 + 0] - pos[r * 3 + 0];
        float dy = pos[c * 3 + 1] - pos[r * 3 + 1];
        float dz = pos[c * 3 + 2] - pos[r * 3 + 2];
        float inv = 1.0f / (sqrtf(dx * dx + dy * dy + dz * dz) + 1e-8f);
        float ux = dx * inv, uy = dy * inv, uz = dz * inv;
        float vix = du[r * 3 + 0], viy = du[r * 3 + 1], viz = du[r * 3 + 2];
        float vjx = du[c * 3 + 0], vjy = du[c * 3 + 1], vjz = du[c * 3 + 2];
        float dvi = vix * ux + viy * uy + viz * uz;
        float dvj = -(vjx * ux + vjy * uy + vjz * uz);
        float wix = vix - dvi * ux, wiy = viy - dvi * uy, wiz = viz - dvi * uz;
        float wjx = vjx + dvj * ux, wjy = vjy + dvj * uy, wjz = vjz + dvj * uz;
        vals[threadIdx.x] = wix * wjx + wiy * wjy + wiz * wjz;
    }
    __syncthreads();
    vfloat4* out = reinterpret_cast<vfloat4*>(dih + (size_t)e0 * HIDDEN);
    #pragma unroll
    for (int it = 0; it < 32; ++it) {
        int i = it * 256 + threadIdx.x;
        float v = vals[i >> 5];
        vfloat4 v4 = {v, v, v, v};
        __builtin_nontemporal_store(v4, out + i);
    }
}

// ---------------------------------------------------------------------------
extern "C" void kernel_launch(void* const* d_in, const int* in_sizes, int n_in,
                              void* d_out, int out_size, void* d_ws, size_t ws_size,
                              hipStream_t stream) {
    const float* pos  = (const float*)d_in[0];
    const int*   eidx = (const int*)d_in[1];

    float* out = (float*)d_out;
    float* ang = out;                                         // (N, 128)
    float* dih = out + (size_t)N_NODES * HIDDEN;              // (E, 128)
    float* du  = dih + (size_t)N_EDGES * HIDDEN;              // (N, 3)

    const size_t need = 1024 + (size_t)NBINS * BIN_CAP * sizeof(unsigned);

    if (ws_size >= need) {
        unsigned* cursors = (unsigned*)d_ws;                  // 256 u32
        unsigned* region  = (unsigned*)d_ws + 256;            // bin regions
        // dvals aliases region: region's last reader is accumulate_kernel,
        // which completes before dihedral_scalar_kernel writes dvals.
        float*    dvals   = (float*)((unsigned*)d_ws + 256);  // (E) scalars

        zero_cursors_kernel<<<1, NBINS, 0, stream>>>(cursors);
        bin_edges_kernel<<<A_BLOCKS, A_THREADS, 0, stream>>>(eidx, cursors, region);
        accumulate_kernel<<<NBINS, B_THREADS, 0, stream>>>(pos, cursors,
                                                           region, du, ang);
        dihedral_scalar_kernel<<<N_EDGES / 256, 256, 0, stream>>>(pos, eidx, du, dvals);
        dihedral_fill_kernel<<<N_EDGES / 256, 256, 0, stream>>>(dvals, dih);
    } else {
        zero_du_kernel<<<(N_NODES * 3 + 255) / 256, 256, 0, stream>>>(du, N_NODES * 3);
        edge_scatter_kernel<<<(N_EDGES + 255) / 256, 256, 0, stream>>>(pos, eidx, du);
        angular_kernel<<<(N_NODES * 32) / 256, 256, 0, stream>>>(du, ang);
        dihedral_fused_kernel<<<N_EDGES / 256, 256, 0, stream>>>(pos, eidx, du, dih);
    }
}